// Round 1
// baseline (416.366 us; speedup 1.0000x reference)
//
#include <hip/hip_runtime.h>

// Problem constants (from reference): N=4194304, C=16, G=8
#define N_ELEMS 4194304
#define C_DIM 16
#define G_NUM 8

// ws layout: [0..7] float sums, [8..15] uint counts  (64 bytes, zeroed via hipMemsetAsync)

__global__ __launch_bounds__(256) void berl_partial(
    const float* __restrict__ input_,
    const int*   __restrict__ target,
    const int*   __restrict__ group,
    float*        __restrict__ g_sums,
    unsigned int* __restrict__ g_counts)
{
    __shared__ float        s_sums[G_NUM];
    __shared__ unsigned int s_counts[G_NUM];
    const int tid = threadIdx.x;
    if (tid < G_NUM) { s_sums[tid] = 0.0f; s_counts[tid] = 0u; }
    __syncthreads();

    // per-thread register accumulators (branchless select, no LDS contention)
    float sums[G_NUM];
    float cnts[G_NUM];
#pragma unroll
    for (int g = 0; g < G_NUM; ++g) { sums[g] = 0.0f; cnts[g] = 0.0f; }

    const int4* t4 = (const int4*)target;
    const int4* g4 = (const int4*)group;
    const int n4     = N_ELEMS / 4;
    const int stride = gridDim.x * blockDim.x;

    for (int i = blockIdx.x * blockDim.x + tid; i < n4; i += stride) {
        int4 t = t4[i];
        int4 g = g4[i];
        const int base = i * (4 * C_DIM);
        float e0 = fabsf(1.0f - __builtin_nontemporal_load(&input_[base + 0 * C_DIM + t.x]));
        float e1 = fabsf(1.0f - __builtin_nontemporal_load(&input_[base + 1 * C_DIM + t.y]));
        float e2 = fabsf(1.0f - __builtin_nontemporal_load(&input_[base + 2 * C_DIM + t.z]));
        float e3 = fabsf(1.0f - __builtin_nontemporal_load(&input_[base + 3 * C_DIM + t.w]));
#pragma unroll
        for (int k = 0; k < G_NUM; ++k) {
            sums[k] += (g.x == k) ? e0 : 0.0f;
            sums[k] += (g.y == k) ? e1 : 0.0f;
            sums[k] += (g.z == k) ? e2 : 0.0f;
            sums[k] += (g.w == k) ? e3 : 0.0f;
            cnts[k] += (g.x == k) ? 1.0f : 0.0f;
            cnts[k] += (g.y == k) ? 1.0f : 0.0f;
            cnts[k] += (g.z == k) ? 1.0f : 0.0f;
            cnts[k] += (g.w == k) ? 1.0f : 0.0f;
        }
    }

    // thread -> block (LDS atomics: 16 per thread)
#pragma unroll
    for (int k = 0; k < G_NUM; ++k) {
        atomicAdd(&s_sums[k], sums[k]);
        atomicAdd(&s_counts[k], (unsigned int)cnts[k]);
    }
    __syncthreads();

    // block -> global (16 atomics per block)
    if (tid < G_NUM) {
        atomicAdd(&g_sums[tid], s_sums[tid]);
        atomicAdd(&g_counts[tid], s_counts[tid]);
    }
}

__global__ void berl_final(const float* __restrict__ g_sums,
                           const unsigned int* __restrict__ g_counts,
                           float* __restrict__ out)
{
    if (threadIdx.x == 0 && blockIdx.x == 0) {
        float acc = 0.0f;
#pragma unroll
        for (int g = 0; g < G_NUM; ++g) {
            float c = (float)g_counts[g];
            float m = (c > 0.0f) ? (g_sums[g] / fmaxf(c, 1.0f)) : 0.0f;
            acc += m;
        }
        out[0] = fabsf(0.5f - acc / (float)G_NUM);
    }
}

extern "C" void kernel_launch(void* const* d_in, const int* in_sizes, int n_in,
                              void* d_out, int out_size, void* d_ws, size_t ws_size,
                              hipStream_t stream) {
    const float* input_ = (const float*)d_in[0];
    const int*   target = (const int*)d_in[1];
    const int*   group  = (const int*)d_in[2];
    float* out = (float*)d_out;

    float*        g_sums   = (float*)d_ws;
    unsigned int* g_counts = (unsigned int*)((char*)d_ws + G_NUM * sizeof(float));

    // zero the 64-byte accumulator region (ws is re-poisoned to 0xAA before every launch)
    hipMemsetAsync(d_ws, 0, G_NUM * (sizeof(float) + sizeof(unsigned int)), stream);

    dim3 block(256);
    dim3 grid(2048);  // 2048*256 threads -> 2 int4-iterations/thread; ~32 waves/CU worth of TLP
    berl_partial<<<grid, block, 0, stream>>>(input_, target, group, g_sums, g_counts);
    berl_final<<<1, 64, 0, stream>>>(g_sums, g_counts, out);
}